// Round 1
// baseline (98.639 us; speedup 1.0000x reference)
//
#include <hip/hip_runtime.h>

#define DCOLS 512
#define NROWS (32 * 4096)
#define GRID1 2048
#define BLOCK1 256
#define WAVES_PER_BLOCK (BLOCK1 / 64)

__global__ __launch_bounds__(BLOCK1) void kld_rows_kernel(
    const float* __restrict__ m1, const float* __restrict__ m2,
    float* __restrict__ partial) {
  const int lane = threadIdx.x & 63;
  const int wave = threadIdx.x >> 6;
  const int gwave = blockIdx.x * WAVES_PER_BLOCK + wave;
  const int nwaves = gridDim.x * WAVES_PER_BLOCK;

  float acc = 0.0f;

  for (int row = gwave; row < NROWS; row += nwaves) {
    const float4* r1 = (const float4*)(m1 + (size_t)row * DCOLS);
    const float4* r2 = (const float4*)(m2 + (size_t)row * DCOLS);
    // 512 floats = 128 float4; lane reads idx lane and lane+64 (coalesced).
    float4 a0 = r1[lane];
    float4 a1 = r1[lane + 64];
    float4 b0 = r2[lane];
    float4 b1 = r2[lane + 64];

    float s1 = (a0.x + a0.y) + (a0.z + a0.w) + (a1.x + a1.y) + (a1.z + a1.w);
    float s2 = (b0.x + b0.y) + (b0.z + b0.w) + (b1.x + b1.y) + (b1.z + b1.w);
    float q1 = 0.0f, q2 = 0.0f;
    q1 = fmaf(a0.x, a0.x, q1); q1 = fmaf(a0.y, a0.y, q1);
    q1 = fmaf(a0.z, a0.z, q1); q1 = fmaf(a0.w, a0.w, q1);
    q1 = fmaf(a1.x, a1.x, q1); q1 = fmaf(a1.y, a1.y, q1);
    q1 = fmaf(a1.z, a1.z, q1); q1 = fmaf(a1.w, a1.w, q1);
    q2 = fmaf(b0.x, b0.x, q2); q2 = fmaf(b0.y, b0.y, q2);
    q2 = fmaf(b0.z, b0.z, q2); q2 = fmaf(b0.w, b0.w, q2);
    q2 = fmaf(b1.x, b1.x, q2); q2 = fmaf(b1.y, b1.y, q2);
    q2 = fmaf(b1.z, b1.z, q2); q2 = fmaf(b1.w, b1.w, q2);

    // Butterfly reduce across the 64-lane wave: all lanes end with totals.
    #pragma unroll
    for (int off = 32; off > 0; off >>= 1) {
      s1 += __shfl_xor(s1, off);
      q1 += __shfl_xor(q1, off);
      s2 += __shfl_xor(s2, off);
      q2 += __shfl_xor(q2, off);
    }

    const float inv_d = 1.0f / (float)DCOLS;
    const float inv_dm1 = 1.0f / (float)(DCOLS - 1);
    float sig1 = s1 * inv_d;              // row mean (acts as sigma diag)
    float sig2 = s2 * inv_d;
    float var1 = (q1 - s1 * s1 * inv_d) * inv_dm1;  // unbiased row variance (acts as mu)
    float var2 = (q2 - s2 * s2 * inv_d) * inv_dm1;

    float sig_avg = 0.5f * (sig1 + sig2);
    float inv_avg = 1.0f / sig_avg;

    // t1_1 + t1_2 = 2*log(sig_avg) - log(sig1) - log(sig2)
    float t1 = __logf((sig_avg * sig_avg) / (sig1 * sig2));
    // t2_1 + t2_2 - 2 (fold the -n constant in per-row to avoid cancellation)
    float t2c = (sig1 + sig2) * inv_avg - 2.0f;
    // t3_1 + t3_2 = 2 * ((var2-var1)/2)^2 * inv_avg
    float dd = 0.5f * (var2 - var1);
    float t3 = 2.0f * dd * dd * inv_avg;

    acc += t1 + t2c + t3;   // identical on all lanes of the wave
  }

  __shared__ float sacc[WAVES_PER_BLOCK];
  if (lane == 0) sacc[wave] = acc;
  __syncthreads();
  if (threadIdx.x == 0) {
    float s = 0.0f;
    #pragma unroll
    for (int w = 0; w < WAVES_PER_BLOCK; ++w) s += sacc[w];
    partial[blockIdx.x] = s;
  }
}

__global__ __launch_bounds__(256) void kld_final_kernel(
    const float* __restrict__ partial, int n, float* __restrict__ out) {
  float s = 0.0f;
  for (int i = threadIdx.x; i < n; i += blockDim.x) s += partial[i];
  #pragma unroll
  for (int off = 32; off > 0; off >>= 1) s += __shfl_xor(s, off);
  __shared__ float red[4];
  const int lane = threadIdx.x & 63;
  const int wave = threadIdx.x >> 6;
  if (lane == 0) red[wave] = s;
  __syncthreads();
  if (threadIdx.x == 0) {
    float t = (red[0] + red[1]) + (red[2] + red[3]);
    // kl_b = 0.25*(sum_rows_in_batch terms); output = mean over 32 batches.
    out[0] = t * (0.25f / 32.0f);
  }
}

extern "C" void kernel_launch(void* const* d_in, const int* in_sizes, int n_in,
                              void* d_out, int out_size, void* d_ws, size_t ws_size,
                              hipStream_t stream) {
  const float* m1 = (const float*)d_in[0];
  const float* m2 = (const float*)d_in[1];
  float* out = (float*)d_out;
  float* partial = (float*)d_ws;  // GRID1 floats = 8 KB

  kld_rows_kernel<<<GRID1, BLOCK1, 0, stream>>>(m1, m2, partial);
  kld_final_kernel<<<1, 256, 0, stream>>>(partial, GRID1, out);
}

// Round 2
// 95.133 us; speedup vs baseline: 1.0368x; 1.0368x over previous
//
#include <hip/hip_runtime.h>

#define DCOLS 512
#define NROWS (32 * 4096)
#define GRID1 2048
#define BLOCK1 256
#define WAVES_PER_BLOCK (BLOCK1 / 64)
#define ROWS_PER_ITER 4   // one row per 16-lane group
#define NWAVES (GRID1 * WAVES_PER_BLOCK)
#define ITERS (NROWS / (NWAVES * ROWS_PER_ITER))  // = 4 exactly

__global__ __launch_bounds__(BLOCK1) void kld_rows_kernel(
    const float* __restrict__ m1, const float* __restrict__ m2,
    float* __restrict__ partial) {
  const int lane = threadIdx.x & 63;
  const int sub  = lane & 15;   // lane within 16-lane row group
  const int grp  = lane >> 4;   // which of the wave's 4 rows
  const int wave = threadIdx.x >> 6;
  const int gwave = blockIdx.x * WAVES_PER_BLOCK + wave;

  float acc = 0.0f;

  #pragma unroll
  for (int i = 0; i < ITERS; ++i) {
    const int row = (i * NWAVES + gwave) * ROWS_PER_ITER + grp;
    const float4* __restrict__ r1 = (const float4*)(m1 + (size_t)row * DCOLS);
    const float4* __restrict__ r2 = (const float4*)(m2 + (size_t)row * DCOLS);

    // 128 float4 per row; 16 lanes x 8 float4 each. All 16 loads issued
    // up front for maximum memory-level parallelism.
    float4 a[8], b[8];
    #pragma unroll
    for (int k = 0; k < 8; ++k) a[k] = r1[sub + k * 16];
    #pragma unroll
    for (int k = 0; k < 8; ++k) b[k] = r2[sub + k * 16];

    float s1 = 0.0f, q1 = 0.0f, s2 = 0.0f, q2 = 0.0f;
    #pragma unroll
    for (int k = 0; k < 8; ++k) {
      s1 += (a[k].x + a[k].y) + (a[k].z + a[k].w);
      q1 = fmaf(a[k].x, a[k].x, q1); q1 = fmaf(a[k].y, a[k].y, q1);
      q1 = fmaf(a[k].z, a[k].z, q1); q1 = fmaf(a[k].w, a[k].w, q1);
    }
    #pragma unroll
    for (int k = 0; k < 8; ++k) {
      s2 += (b[k].x + b[k].y) + (b[k].z + b[k].w);
      q2 = fmaf(b[k].x, b[k].x, q2); q2 = fmaf(b[k].y, b[k].y, q2);
      q2 = fmaf(b[k].z, b[k].z, q2); q2 = fmaf(b[k].w, b[k].w, q2);
    }

    // Reduce within each 16-lane group: 4 steps x 4 values.
    #pragma unroll
    for (int off = 8; off > 0; off >>= 1) {
      s1 += __shfl_xor(s1, off);
      q1 += __shfl_xor(q1, off);
      s2 += __shfl_xor(s2, off);
      q2 += __shfl_xor(q2, off);
    }

    const float inv_d = 1.0f / (float)DCOLS;
    const float inv_dm1 = 1.0f / (float)(DCOLS - 1);
    float sig1 = s1 * inv_d;                         // row mean ("sigma" diag)
    float sig2 = s2 * inv_d;
    float var1 = (q1 - s1 * s1 * inv_d) * inv_dm1;   // unbiased variance ("mu")
    float var2 = (q2 - s2 * s2 * inv_d) * inv_dm1;

    float sig_avg = 0.5f * (sig1 + sig2);
    float inv_avg = 1.0f / sig_avg;

    // t1_1+t1_2 = 2*log(sig_avg) - log(sig1) - log(sig2)
    float t1 = __logf((sig_avg * sig_avg) / (sig1 * sig2));
    // t2_1+t2_2-2 folded per-row (avoids 2048.x - 2048 cancellation at the end)
    float t2c = (sig1 + sig2) * inv_avg - 2.0f;
    // t3_1+t3_2 = 2*((var2-var1)/2)^2 * inv_avg
    float dd = 0.5f * (var2 - var1);
    float t3 = 2.0f * dd * dd * inv_avg;

    acc += t1 + t2c + t3;   // identical across the 16 lanes of this group
  }

  // Sum across the wave's 4 groups (each group's lanes hold identical acc).
  acc += __shfl_xor(acc, 16);
  acc += __shfl_xor(acc, 32);

  __shared__ float sacc[WAVES_PER_BLOCK];
  if (lane == 0) sacc[wave] = acc;
  __syncthreads();
  if (threadIdx.x == 0) {
    float s = 0.0f;
    #pragma unroll
    for (int w = 0; w < WAVES_PER_BLOCK; ++w) s += sacc[w];
    partial[blockIdx.x] = s;
  }
}

__global__ __launch_bounds__(256) void kld_final_kernel(
    const float* __restrict__ partial, int n, float* __restrict__ out) {
  float s = 0.0f;
  for (int i = threadIdx.x; i < n; i += blockDim.x) s += partial[i];
  #pragma unroll
  for (int off = 32; off > 0; off >>= 1) s += __shfl_xor(s, off);
  __shared__ float red[4];
  const int lane = threadIdx.x & 63;
  const int wave = threadIdx.x >> 6;
  if (lane == 0) red[wave] = s;
  __syncthreads();
  if (threadIdx.x == 0) {
    float t = (red[0] + red[1]) + (red[2] + red[3]);
    out[0] = t * (0.25f / 32.0f);   // 0.25 * sum, then mean over 32 batches
  }
}

extern "C" void kernel_launch(void* const* d_in, const int* in_sizes, int n_in,
                              void* d_out, int out_size, void* d_ws, size_t ws_size,
                              hipStream_t stream) {
  const float* m1 = (const float*)d_in[0];
  const float* m2 = (const float*)d_in[1];
  float* out = (float*)d_out;
  float* partial = (float*)d_ws;  // GRID1 floats = 8 KB

  kld_rows_kernel<<<GRID1, BLOCK1, 0, stream>>>(m1, m2, partial);
  kld_final_kernel<<<1, 256, 0, stream>>>(partial, GRID1, out);
}